// Round 15
// baseline (245.450 us; speedup 1.0000x reference)
//
#include <hip/hip_runtime.h>

#define GH 135
#define GW 240
#define HH 1080
#define WW 1920
#define HWPX (HH*WW)
#define NP 12
#define IT 6               // anchor block-rows per WG
#define JT 6               // anchor blocks (j) per WG
#define NTG 2              // anchor TRIPLES per it-row (3 anchors/thread)
#define NIG 23             // ceil(GH/IT), last strip ragged (guarded)
#define NJG 40             // GW/JT
#define TROWS (IT+8)       // 14 staged target block-rows
#define TBLK (JT+8)        // 14 REAL staged target blocks per dy-row
#define TSBLK 16           // STORED blocks per row (padded so UNITS_ROW=256
                           // = exactly 4 waves -> global_load_lds wave-uniform
                           // base rule holds; r14's 224=3.5 waves corrupted
                           // every straddling wave's row -> absmax 1.0)
#define DSTR (TSBLK*64+8)  // 1032 dw: dr*1032 %32 = 8*dr -> 2-quad rotation (r12)
#define UNITS_ROW (TSBLK*16) // 256 16B-units per dy-row = 4 waves exactly
#define UNITS_TOT (TROWS*UNITS_ROW) // 3584 = 14 full 256-thread iterations
#define NTHR 256
#define NACT 216           // 9 dy * (6 it * 2 tg * 2 yh) = 84% active
#define TT_DW (TROWS*DSTR) // 14448 dw = 57792 B -> 2 WG/CU at VGPR 128
#define NWG (NIG*NJG)      // 920 = 8*115 (XCD-exact)

// Round-15 = round-14 with the DMA wave-uniform-base bug fixed by row padding.
// A=3 anchor windows (9.8 px/b128, LDS traffic x0.73 vs champion) in the
// feasible envelope: NACT=216/256, (256,2) -> VGPR cap 128 (r9 measured this
// inner loop at exactly 128, zero spill), async global_load_lds staging with
// clamped src (r11), 2-quad row rotation (r12).
// Swizzled storage (bijective involution, proven r5/r12), per block-row:
//   stored(blk,y,xh) = blk*64 + ((y*8+xh) ^ 4*kb ^ 16*(y>>2)), kb=(blk>>1)&7

// 8-px fp32 chain + f64 accumulate (argmin-exact vs np reference, proven r1-r13)
#define CHAIN(AV0, AV1, T0, T1, ACC) do { \
    float _d = (AV0).x - (T0).x; float _s = _d*_d; \
    _d = (AV0).y - (T0).y; _s = fmaf(_d,_d,_s); \
    _d = (AV0).z - (T0).z; _s = fmaf(_d,_d,_s); \
    _d = (AV0).w - (T0).w; _s = fmaf(_d,_d,_s); \
    _d = (AV1).x - (T1).x; _s = fmaf(_d,_d,_s); \
    _d = (AV1).y - (T1).y; _s = fmaf(_d,_d,_s); \
    _d = (AV1).z - (T1).z; _s = fmaf(_d,_d,_s); \
    _d = (AV1).w - (T1).w; _s = fmaf(_d,_d,_s); \
    (ACC) += (double)_s; } while(0)

__device__ __forceinline__ void async_copy16(const float* gp, float* lp) {
#if __has_builtin(__builtin_amdgcn_global_load_lds)
    __builtin_amdgcn_global_load_lds(
        (const __attribute__((address_space(1))) void*)gp,
        (__attribute__((address_space(3))) void*)lp, 16, 0, 0);
#else
    *(float4*)lp = *(const float4*)gp;
#endif
}

__global__ void __launch_bounds__(NTHR, 2)
hbma_cost_kernel(const float* __restrict__ A, const float* __restrict__ T,
                 int* __restrict__ bestidx) {
    extern __shared__ float lds[];
    float* Tt = lds;

    // XCD swizzle: 920 WGs = 8 XCDs x 115
    const int lin = blockIdx.x;
    const int g   = (lin & 7) * (NWG / 8) + (lin >> 3);
    const int ig  = g % NIG, jg = g / NIG;
    const int i0  = ig * IT;
    const int j0  = jg * JT;

    const int tid = threadIdx.x;
    const int dy  = tid / 24;          // 0..8 for active threads
    const int rem = tid % 24;
    const int it  = rem >> 2;          // 0..5
    const int r2  = rem & 3;
    const int tg  = r2 >> 1;           // 0..1 (anchor triple)
    const int yh  = r2 & 1;            // y-half
    const bool act = (tid < NACT);
    const int i   = i0 + it;           // may be >= GH on last strip (guarded)
    const int gi  = i + dy - 4;
    const bool dyValid = act && (i < GH) && (gi >= 0) && (gi < GH);
    const int dr  = it + dy;           // staged row index 0..13
    const int jb0 = j0 + 3 * tg;       // first anchor block of this thread

    // per-p read XOR (window base 3*tg may be odd); static-indexed -> registers
    int xq2[11];
#pragma unroll
    for (int p = 0; p < 11; ++p)
        xq2[p] = ((((3 * tg + p) >> 1) & 7) * 4) ^ (yh << 4);

    double acc[3][9];
#pragma unroll
    for (int a = 0; a < 3; ++a)
#pragma unroll
        for (int d = 0; d < 9; ++d) acc[a][d] = 0.0;

    const int gy0 = (i0 - 4) * 8;
    const int gx0 = (j0 - 4) * 8;

    for (int q = 0; q < NP; ++q) {
        const float* Tq = T + (size_t)q * HWPX;
        const float* Aq = A + (size_t)q * HWPX;
        __syncthreads();               // prev compute done before LDS overwrite
        // ---- stage target halo: async DMA, linear dest units, clamped src.
        //      Exactly 14 iterations; each iteration = one full row (256 units
        //      = 4 whole waves) -> wave-uniform-base rule satisfied. ----
#pragma unroll 1
        for (int k = 0; k < TROWS; ++k) {
            const int u   = tid;                        // unit within row k
            const int blk = u >> 4, v = u & 15;
            const int kb  = (blk >> 1) & 7;
            const int yh2 = v >> 3;
            const int m3  = (v & 7) ^ kb ^ (yh2 << 2);
            const int y   = (yh2 << 2) + (m3 >> 1);
            const int xh4 = m3 & 1;
            int gy = gy0 + k * 8 + y;
            int gx = gx0 + blk * 8 + xh4 * 4;           // blk 14/15 = pad, never read
            gy = min(max(gy, 0), HH - 1);               // clamp: garbage slots
            gx = min(max(gx, 0), WW - 4);               // are argmin-masked (r11)
            async_copy16(Tq + (size_t)gy * WW + gx, Tt + k * DSTR + u * 4);
        }
        __syncthreads();               // auto vmcnt(0): DMA landed
        // ---- SSD: sliding 11-block window serves 3 anchors x 9 dx ----
        if (dyValid) {
            const float* tb = Tt + dr * DSTR + (3 * tg) * 64 + yh * 32;
#pragma unroll
            for (int yi = 0; yi < 4; ++yi) {
                // anchor rows for this yi (6 f4 live; L1-hot, 9x dy-redundant)
                float4 aw[3][2];
#pragma unroll
                for (int a = 0; a < 3; ++a) {
                    const float* row = Aq + (size_t)(jb0 + a) * 8
                                     + (size_t)(i * 8 + yh * 4 + yi) * WW;
                    aw[a][0] = *(const float4*)(row);
                    aw[a][1] = *(const float4*)(row + 4);
                }
                // p-chunks of 4/4/3: bounded tw pressure, deep ds ILP
#pragma unroll
                for (int ph = 0; ph < 3; ++ph) {
                    const int pc = (ph < 2) ? 4 : 3;
                    float4 tw0[4], tw1[4];
#pragma unroll
                    for (int pp = 0; pp < 4; ++pp) {
                        if (pp < pc) {
                            const int p  = ph * 4 + pp;
                            const int o0 = (yi * 8) ^ xq2[p];
                            tw0[pp] = *(const float4*)(tb + p * 64 + o0);
                            tw1[pp] = *(const float4*)(tb + p * 64 + (o0 ^ 4));
                        }
                    }
#pragma unroll
                    for (int pp = 0; pp < 4; ++pp) {
                        if (pp < pc) {
                            const int p = ph * 4 + pp;
#pragma unroll
                            for (int a = 0; a < 3; ++a) {
                                const int dxi = p - a;
                                if (dxi >= 0 && dxi < 9)
                                    CHAIN(aw[a][0], aw[a][1], tw0[pp], tw1[pp], acc[a][dxi]);
                            }
                        }
                    }
                }
            }
        }
    }
    // ---- y-half merge via LDS (aliases Tt, barrier-protected) ----
    __syncthreads();
    double* yred = (double*)lds;                     // 108 groups * 27 f64 = 5832 dw
    const int grpId = (it * NTG + tg) * 9 + dy;      // 0..107
    if (act && yh == 1) {
        double* d = yred + grpId * 27;
#pragma unroll
        for (int a = 0; a < 3; ++a)
#pragma unroll
            for (int k = 0; k < 9; ++k) d[a * 9 + k] = acc[a][k];
    }
    __syncthreads();
    double* redc = (double*)(lds + 8192);            // 324 f64 = 648 dw
    int*    redk = (int*)(lds + 8192 + 648);         // 324 int
    if (act && yh == 0) {
        const double* d = yred + grpId * 27;
#pragma unroll
        for (int a = 0; a < 3; ++a)
#pragma unroll
            for (int k = 0; k < 9; ++k) acc[a][k] += d[a * 9 + k];
        // stage-1 argmin over dx (ascending, strict < -> first-k ties)
#pragma unroll
        for (int a = 0; a < 3; ++a) {
            double bc = 1e300; int bk = -1;
            const int jb = jb0 + a;
#pragma unroll
            for (int dxi = 0; dxi < 9; ++dxi) {
                const int gj = jb + dxi - 4;
                if (dyValid && gj >= 0 && gj < GW && acc[a][dxi] < bc) {
                    bc = acc[a][dxi]; bk = dy * 9 + dxi;
                }
            }
            redc[(it * 9 + dy) * JT + 3 * tg + a] = bc;
            redk[(it * 9 + dy) * JT + 3 * tg + a] = bk;
        }
    }
    __syncthreads();
    // ---- stage-2 argmin over dy (ascending, strict <) ----
    if (tid < IT * JT) {
        const int it2 = tid / JT, jt = tid % JT;
        if (i0 + it2 < GH) {
            double c = 1e300; int k = -1;
#pragma unroll
            for (int dyi = 0; dyi < 9; ++dyi) {
                const double v = redc[(it2 * 9 + dyi) * JT + jt];
                if (v < c) { c = v; k = redk[(it2 * 9 + dyi) * JT + jt]; }
            }
            const int dyi = k / 9, dxi = k % 9;
            const int bi = i0 + it2 + dyi - 4;
            const int bj = j0 + jt + dxi - 4;
            bestidx[(i0 + it2) * GW + j0 + jt] = (bi << 8) | bj;
        }
    }
}

__global__ void __launch_bounds__(256) hbma_gather_kernel(const float* __restrict__ A,
                                                          const int* __restrict__ bestidx,
                                                          float* __restrict__ out) {
    const int tid = blockIdx.x * 256 + threadIdx.x;
    const int q   = tid / (HWPX / 4);
    const int rem = tid % (HWPX / 4);
    const int py  = rem / (WW / 4);
    const int c4  = rem % (WW / 4);
    const int i = py >> 3, y = py & 7;
    const int j = c4 >> 1, xh = (c4 & 1) * 4;
    const int idx = bestidx[i * GW + j];
    const int bi = idx >> 8, bj = idx & 255;
    const float4 v = *(const float4*)(A + (size_t)q * HWPX + (size_t)(bi * 8 + y) * WW + bj * 8 + xh);
    *(float4*)(out + (size_t)q * HWPX + (size_t)py * WW + c4 * 4) = v;
}

extern "C" void kernel_launch(void* const* d_in, const int* in_sizes, int n_in,
                              void* d_out, int out_size, void* d_ws, size_t ws_size,
                              hipStream_t stream) {
    const float* A = (const float*)d_in[0];
    const float* T = (const float*)d_in[1];
    float* out = (float*)d_out;
    int* bestidx = (int*)d_ws;

    hipFuncSetAttribute((const void*)hbma_cost_kernel,
                        hipFuncAttributeMaxDynamicSharedMemorySize, TT_DW * 4);

    hipLaunchKernelGGL(hbma_cost_kernel, dim3(NWG), dim3(NTHR), TT_DW * 4, stream,
                       A, T, bestidx);

    const int total4 = (NP * HWPX) / 4;
    hipLaunchKernelGGL(hbma_gather_kernel, dim3(total4 / 256), dim3(256), 0, stream,
                       A, bestidx, out);
}